// Round 4
// baseline (435.172 us; speedup 1.0000x reference)
//
#include <hip/hip_runtime.h>
#include <hip/hip_bf16.h>
#include <math.h>

#define Bq 256
#define Tq 256
#define Hq 512
#define Eq 96

typedef __attribute__((ext_vector_type(8))) short short8;
typedef __attribute__((ext_vector_type(4))) float f32x4;

static __device__ __forceinline__ unsigned short f2bf(float f) {
  union { float f; unsigned u; } v; v.f = f;
  unsigned r = v.u + 0x7FFF + ((v.u >> 16) & 1);
  return (unsigned short)(r >> 16);
}

static __device__ __forceinline__ ushort4 pack4(float4 v) {
  ushort4 p;
  p.x = f2bf(v.x); p.y = f2bf(v.y); p.z = f2bf(v.z); p.w = f2bf(v.w);
  return p;
}

static __device__ __forceinline__ float sat_tanh(float x) {
  float ax = fminf(fabsf(x), 15.0f);
  float e = __builtin_exp2f(ax * 2.885390082f);
  float t = 1.0f - 2.0f / (e + 1.0f);
  return copysignf(t, x);
}

static __device__ __forceinline__ float sat_sig(float x) {
  float cx = fmaxf(fminf(x, 30.0f), -30.0f);
  return 1.0f / (1.0f + __builtin_exp2f(-cx * 1.442695041f));
}

// ---------------- K0: W_i2h fp32 [K][N] -> bf16 transposed [N][K] ----------
__global__ __launch_bounds__(256) void convW_k(const float* __restrict__ W,
                                               unsigned short* __restrict__ Wt) {
  __shared__ float tile[32][33];
  int bx = blockIdx.x & 15, by = blockIdx.x >> 4;
  int tx = threadIdx.x & 31, ty = threadIdx.x >> 5;
  #pragma unroll
  for (int i = 0; i < 32; i += 8)
    tile[ty + i][tx] = W[(size_t)(by * 32 + ty + i) * Hq + bx * 32 + tx];
  __syncthreads();
  #pragma unroll
  for (int i = 0; i < 32; i += 8)
    Wt[(size_t)(bx * 32 + ty + i) * Hq + by * 32 + tx] = f2bf(tile[tx][ty + i]);
}

// ---------------- K1: hp partial GEMM, K-split, atomicAdd ------------------
__global__ __launch_bounds__(256) void hsplit_k(const float* __restrict__ ph,
                                                const float* __restrict__ Whh,
                                                float* __restrict__ hp) {
  __shared__ __align__(16) float xs[8][128];
  const int ks = blockIdx.x & 3;
  const int nc = (blockIdx.x >> 2) & 3;
  const int bg = blockIdx.x >> 4;
  const int tid = threadIdx.x;
  const int row0 = bg * 8;
  const int d0 = ks * 128;
  for (int i = tid; i < 8 * 32; i += 256) {
    int r = i >> 5, dd = (i & 31) * 4;
    *(float4*)&xs[r][dd] = *(const float4*)&ph[(size_t)(row0 + r) * Hq + d0 + dd];
  }
  __syncthreads();
  const int rt = tid >> 6;
  const int ct = tid & 63;
  const int n = nc * 128 + ct * 2;
  float a00 = 0, a01 = 0, a10 = 0, a11 = 0;
  for (int dd = 0; dd < 128; dd += 4) {
    float4 x0 = *(const float4*)&xs[rt * 2][dd];
    float4 x1 = *(const float4*)&xs[rt * 2 + 1][dd];
    #pragma unroll
    for (int j = 0; j < 4; j++) {
      float2 w = *(const float2*)&Whh[(size_t)(d0 + dd + j) * Hq + n];
      float xj0 = ((const float*)&x0)[j];
      float xj1 = ((const float*)&x1)[j];
      a00 += xj0 * w.x; a01 += xj0 * w.y;
      a10 += xj1 * w.x; a11 += xj1 * w.y;
    }
  }
  int row = row0 + rt * 2;
  atomicAdd(&hp[(size_t)row * Hq + n], a00);
  atomicAdd(&hp[(size_t)row * Hq + n + 1], a01);
  atomicAdd(&hp[(size_t)(row + 1) * Hq + n], a10);
  atomicAdd(&hp[(size_t)(row + 1) * Hq + n + 1], a11);
}

// ---------------- K2 v4: 2-phase double-buffered proj GEMM + score ---------
// BM=128 x BN=256, BK=32, 1024 thr / 16 waves (2m x 8n), acc[4][2]/wave.
// Per step: issue global loads(k+1) -> ds_read frags(k) -> MFMA ->
// convert+ds_write(k+1) into other buffer -> ONE barrier. Loads for k+1
// are covered by step k's compute (register-dep gating, no vmcnt(0) drain).
// LDK=40 pad: frag reads 16B-aligned, 2-way bank alias = free.
#define LDK4 40

__global__ __launch_bounds__(1024, 4) void fused_score4_k(
    const float* __restrict__ A,
    const unsigned short* __restrict__ Wt,
    const float* __restrict__ hp,
    const float* __restrict__ bh,
    const float* __restrict__ wsc,
    float* __restrict__ e) {
  __shared__ unsigned short As[2][128 * LDK4];  // 20480 B
  __shared__ unsigned short Bs[2][256 * LDK4];  // 40960 B
  __shared__ float red[8][128];                 // 4096 B

  const int tid = threadIdx.x;
  const int n0 = blockIdx.x * 256;   // 0 or 256
  const int m0 = blockIdx.y * 128;
  const int b = m0 >> 8;
  const int wave = tid >> 6;
  const int lane = tid & 63;
  const int quad = lane >> 4;
  const int l16 = lane & 15;
  const int wm = wave >> 3;          // 0..1 : row half
  const int wn8 = wave & 7;          // 0..7 : 32-col chunk

  // staging coords: A 128x32 fp32 (1 float4/thr), B 256x32 bf16 (1 uint4/thr)
  const int ar = tid >> 3, ac = (tid & 7) * 4;
  const int bc = tid >> 2, bk = (tid & 3) * 8;
  const float* Agp = A + (size_t)(m0 + ar) * Hq + ac;
  const unsigned short* Bgp = Wt + (size_t)(n0 + bc) * Hq + bk;

  f32x4 acc[4][2] = {};

  // prologue: stage k=0 into buffer 0
  {
    float4 a0 = *(const float4*)Agp;
    uint4 b0 = *(const uint4*)Bgp;
    *(ushort4*)&As[0][ar * LDK4 + ac] = pack4(a0);
    *(uint4*)&Bs[0][bc * LDK4 + bk] = b0;
  }
  __syncthreads();

  int cur = 0;
  #pragma unroll 2
  for (int ks = 0; ks < 16; ks++) {
    float4 an;
    uint4 bn;
    if (ks < 15) {
      an = *(const float4*)(Agp + (ks + 1) * 32);
      bn = *(const uint4*)(Bgp + (ks + 1) * 32);
    }

    short8 af[4], bf[2];
    #pragma unroll
    for (int mi = 0; mi < 4; mi++)
      af[mi] = *(const short8*)&As[cur][(wm * 64 + mi * 16 + l16) * LDK4 + quad * 8];
    #pragma unroll
    for (int ni = 0; ni < 2; ni++)
      bf[ni] = *(const short8*)&Bs[cur][(wn8 * 32 + ni * 16 + l16) * LDK4 + quad * 8];

    #pragma unroll
    for (int mi = 0; mi < 4; mi++)
      #pragma unroll
      for (int ni = 0; ni < 2; ni++)
        acc[mi][ni] = __builtin_amdgcn_mfma_f32_16x16x32_bf16(
            af[mi], bf[ni], acc[mi][ni], 0, 0, 0);

    if (ks < 15) {
      *(ushort4*)&As[cur ^ 1][ar * LDK4 + ac] = pack4(an);
      *(uint4*)&Bs[cur ^ 1][bc * LDK4 + bk] = bn;
    }
    __syncthreads();
    cur ^= 1;
  }

  // epilogue: tanh + w_score dot over this wave's 32 cols, reduce, atomic e
  float hv[2], wv[2];
  #pragma unroll
  for (int ni = 0; ni < 2; ni++) {
    int c = n0 + wn8 * 32 + ni * 16 + l16;
    hv[ni] = hp[(size_t)b * Hq + c] + bh[c];
    wv[ni] = wsc[c];
  }
  #pragma unroll
  for (int mi = 0; mi < 4; mi++) {
    float s[4] = {0, 0, 0, 0};
    #pragma unroll
    for (int ni = 0; ni < 2; ni++)
      #pragma unroll
      for (int r = 0; r < 4; r++)
        s[r] += sat_tanh(acc[mi][ni][r] + hv[ni]) * wv[ni];
    #pragma unroll
    for (int r = 0; r < 4; r++) {
      s[r] += __shfl_xor(s[r], 8, 64);
      s[r] += __shfl_xor(s[r], 4, 64);
      s[r] += __shfl_xor(s[r], 2, 64);
      s[r] += __shfl_xor(s[r], 1, 64);
    }
    if (l16 == 0) {
      #pragma unroll
      for (int r = 0; r < 4; r++)
        red[wn8][wm * 64 + mi * 16 + quad * 4 + r] = s[r];
    }
  }
  __syncthreads();
  if (tid < 128) {
    float t = 0.f;
    #pragma unroll
    for (int w8 = 0; w8 < 8; w8++) t += red[w8][tid];
    atomicAdd(&e[m0 + tid], t);
  }
}

// ---------------- K3: softmax over T per batch, IN PLACE -------------------
__global__ __launch_bounds__(256) void softmax_k(float* __restrict__ ea) {
  __shared__ float red[8];
  int b = blockIdx.x, t = threadIdx.x;
  int wave = t >> 6, lane = t & 63;
  float x = ea[b * Tq + t];
  float m = x;
  #pragma unroll
  for (int off = 32; off >= 1; off >>= 1) m = fmaxf(m, __shfl_xor(m, off, 64));
  if (lane == 0) red[wave] = m;
  __syncthreads();
  m = fmaxf(fmaxf(red[0], red[1]), fmaxf(red[2], red[3]));
  float ex = __builtin_exp2f((x - m) * 1.442695041f);
  float s = ex;
  #pragma unroll
  for (int off = 32; off >= 1; off >>= 1) s += __shfl_xor(s, off, 64);
  if (lane == 0) red[4 + wave] = s;
  __syncthreads();
  s = red[4] + red[5] + red[6] + red[7];
  ea[b * Tq + t] = ex / s;
}

// ---------------- K4: context partials, T-split, float4, atomicAdd ---------
__global__ __launch_bounds__(256) void ctxsplit_k(const float* __restrict__ alpha,
                                                  const float* __restrict__ bH,
                                                  float* __restrict__ ctx) {
  __shared__ float al[64];
  const int b = blockIdx.x >> 2;
  const int tc = blockIdx.x & 3;
  const int tid = threadIdx.x;
  if (tid < 64) al[tid] = alpha[b * Tq + tc * 64 + tid];
  __syncthreads();
  const float* Hp = bH + (size_t)b * Tq * Hq + (size_t)tc * 64 * Hq;
  const int h4 = (tid & 127) * 4;
  const int t0 = (tid >> 7) * 32;   // 0 or 32
  float a0 = 0.f, a1 = 0.f, a2 = 0.f, a3 = 0.f;
  #pragma unroll 8
  for (int t = 0; t < 32; t++) {
    float a = al[t0 + t];
    float4 v = *(const float4*)&Hp[(size_t)(t0 + t) * Hq + h4];
    a0 += a * v.x; a1 += a * v.y; a2 += a * v.z; a3 += a * v.w;
  }
  float* cp = &ctx[(size_t)b * Hq + h4];
  atomicAdd(cp + 0, a0);
  atomicAdd(cp + 1, a1);
  atomicAdd(cp + 2, a2);
  atomicAdd(cp + 3, a3);
}

// ---------------- K5a: z partial GEMM, 32-row blocks, K-split, atomic ------
// grid 256: bg(8) x hc(8) x ks(4). Block 512 thr: 32 rows x 256 cols x 280 k.
// Weights read 8x total (was 32x). x reads broadcast across each wave.
__global__ __launch_bounds__(512) void zsplit_k(
    const float* __restrict__ ctx, const float* __restrict__ oneh,
    const float* __restrict__ ph, const float* __restrict__ Wl,
    const float* __restrict__ Ul, float* __restrict__ z) {
  __shared__ float xs[32 * 280];   // 35840 B
  const int ks = blockIdx.x & 3;
  const int hc = (blockIdx.x >> 2) & 7;
  const int bg = blockIdx.x >> 5;          // 0..7
  const int tid = threadIdx.x;
  const int row0 = bg * 32;
  const int dbase = ks * 280;

  for (int i = tid; i < 32 * 280; i += 512) {
    int r = i / 280, dd = i % 280;
    int g = dbase + dd;
    float v;
    if (g < 512) v = ctx[(size_t)(row0 + r) * Hq + g];
    else if (g < 608) v = oneh[(row0 + r) * Eq + (g - 512)];
    else v = ph[(size_t)(row0 + r) * Hq + (g - 608)];
    xs[r * 280 + dd] = v;
  }
  __syncthreads();

  const int rt = tid >> 6;     // 0..7 -> rows rt*4 .. rt*4+3
  const int ct = tid & 63;
  const int c0 = ct * 4;
  const int gate = c0 >> 6;
  const int ho = c0 & 63;
  const int n = gate * 512 + hc * 64 + ho;

  float acc[4][4] = {};
  #pragma unroll 4
  for (int dd = 0; dd < 280; dd++) {
    int g = dbase + dd;
    const float* wp = (g < 608) ? &Wl[(size_t)g * 2048 + n]
                                : &Ul[(size_t)(g - 608) * 2048 + n];
    float4 w = *(const float4*)wp;
    #pragma unroll
    for (int r = 0; r < 4; r++) {
      float x = xs[(rt * 4 + r) * 280 + dd];
      acc[r][0] += x * w.x; acc[r][1] += x * w.y;
      acc[r][2] += x * w.z; acc[r][3] += x * w.w;
    }
  }
  #pragma unroll
  for (int r = 0; r < 4; r++) {
    float* zp = &z[(size_t)(row0 + rt * 4 + r) * 2048 + n];
    #pragma unroll
    for (int j = 0; j < 4; j++) atomicAdd(zp + j, acc[r][j]);
  }
}

// ---------------- K5b: gates from z ----------------------------------------
__global__ __launch_bounds__(256) void gatesz_k(const float* __restrict__ z,
                                                const float* __restrict__ bl,
                                                const float* __restrict__ pc,
                                                float* __restrict__ outh,
                                                float* __restrict__ outc) {
  int p = blockIdx.x * 256 + threadIdx.x;
  #pragma unroll
  for (int q = 0; q < 2; q++, p += 65536) {
    int r = p >> 9, h = p & 511;
    const float* zb = z + (size_t)r * 2048;
    float gi = zb[h] + bl[h];
    float gf = zb[512 + h] + bl[512 + h];
    float gg = zb[1024 + h] + bl[1024 + h];
    float go = zb[1536 + h] + bl[1536 + h];
    float cn = sat_sig(gf) * pc[p] + sat_sig(gi) * sat_tanh(gg);
    float hn = sat_sig(go) * sat_tanh(cn);
    outh[p] = hn;
    outc[p] = cn;
  }
}

// ---------------- fallback K5 (ws too small for z): fused z-GEMM+gates -----
#define KXc 1120
__global__ __launch_bounds__(256) void zgates2_k(
    const float* __restrict__ ctx, const float* __restrict__ oneh,
    const float* __restrict__ ph, const float* __restrict__ pc,
    const float* __restrict__ Wl, const float* __restrict__ Ul,
    const float* __restrict__ bl,
    float* __restrict__ outh, float* __restrict__ outc) {
  __shared__ __align__(16) float xs[8 * KXc];
  const int bg = blockIdx.x >> 3;
  const int hc = blockIdx.x & 7;
  const int tid = threadIdx.x;
  const int row0 = bg * 8;

  for (int i = tid; i < 8 * 128; i += 256) {
    int r = i >> 7, dd = (i & 127) * 4;
    *(float4*)&xs[r * KXc + dd] = *(const float4*)&ctx[(size_t)(row0 + r) * Hq + dd];
  }
  for (int i = tid; i < 8 * 128; i += 256) {
    int r = i >> 7, dd = (i & 127) * 4;
    *(float4*)&xs[r * KXc + 608 + dd] = *(const float4*)&ph[(size_t)(row0 + r) * Hq + dd];
  }
  if (tid < 8 * 24) {
    int r = tid / 24, dd = (tid % 24) * 4;
    *(float4*)&xs[r * KXc + 512 + dd] = *(const float4*)&oneh[(row0 + r) * Eq + dd];
  }
  __syncthreads();

  const int rt = tid >> 6;
  const int ct = tid & 63;
  const int c0 = ct * 4;
  const int gate = c0 >> 6;
  const int ho = c0 & 63;
  const int n = gate * 512 + hc * 64 + ho;

  float acc0[4] = {0, 0, 0, 0};
  float acc1[4] = {0, 0, 0, 0};
  const float* xr0 = &xs[(rt * 2) * KXc];
  const float* xr1 = &xs[(rt * 2 + 1) * KXc];

  for (int d = 0; d < 608; d += 4) {
    float4 x0 = *(const float4*)&xr0[d];
    float4 x1 = *(const float4*)&xr1[d];
    #pragma unroll
    for (int j = 0; j < 4; j++) {
      float4 w = *(const float4*)&Wl[(size_t)(d + j) * 2048 + n];
      float a = ((const float*)&x0)[j], b = ((const float*)&x1)[j];
      acc0[0] += a * w.x; acc0[1] += a * w.y; acc0[2] += a * w.z; acc0[3] += a * w.w;
      acc1[0] += b * w.x; acc1[1] += b * w.y; acc1[2] += b * w.z; acc1[3] += b * w.w;
    }
  }
  for (int d = 0; d < 512; d += 4) {
    float4 x0 = *(const float4*)&xr0[608 + d];
    float4 x1 = *(const float4*)&xr1[608 + d];
    #pragma unroll
    for (int j = 0; j < 4; j++) {
      float4 w = *(const float4*)&Ul[(size_t)(d + j) * 2048 + n];
      float a = ((const float*)&x0)[j], b = ((const float*)&x1)[j];
      acc0[0] += a * w.x; acc0[1] += a * w.y; acc0[2] += a * w.z; acc0[3] += a * w.w;
      acc1[0] += b * w.x; acc1[1] += b * w.y; acc1[2] += b * w.z; acc1[3] += b * w.w;
    }
  }

  __syncthreads();
  float* zs = xs;
  #pragma unroll
  for (int j = 0; j < 4; j++) {
    zs[(rt * 2) * 256 + c0 + j] = acc0[j];
    zs[(rt * 2 + 1) * 256 + c0 + j] = acc1[j];
  }
  __syncthreads();

  #pragma unroll
  for (int p = tid; p < 512; p += 256) {
    int r = p >> 6, o = p & 63;
    int h = hc * 64 + o;
    int grow = row0 + r;
    float gi = zs[r * 256 + o]       + bl[h];
    float gf = zs[r * 256 + 64 + o]  + bl[512 + h];
    float gg = zs[r * 256 + 128 + o] + bl[1024 + h];
    float go = zs[r * 256 + 192 + o] + bl[1536 + h];
    float cn = sat_sig(gf) * pc[(size_t)grow * Hq + h] + sat_sig(gi) * sat_tanh(gg);
    float hn = sat_sig(go) * sat_tanh(cn);
    outh[(size_t)grow * Hq + h] = hn;
    outc[(size_t)grow * Hq + h] = cn;
  }
}

extern "C" void kernel_launch(void* const* d_in, const int* in_sizes, int n_in,
                              void* d_out, int out_size, void* d_ws, size_t ws_size,
                              hipStream_t stream) {
  const float* prev_h = (const float*)d_in[0];
  const float* prev_c = (const float*)d_in[1];
  const float* batch_H = (const float*)d_in[2];
  const float* oneh = (const float*)d_in[3];
  const float* W_i2h = (const float*)d_in[4];
  const float* W_h2h = (const float*)d_in[5];
  const float* b_h2h = (const float*)d_in[6];
  const float* w_score = (const float*)d_in[7];
  const float* W_lstm = (const float*)d_in[8];
  const float* U_lstm = (const float*)d_in[9];
  const float* b_lstm = (const float*)d_in[10];

  float* out = (float*)d_out;
  float* outh = out;
  float* outc = out + Bq * Hq;
  float* alpha = out + 2 * Bq * Hq;

  // ws layout: [0,512K) hp -> ctx; [512K,1M) Wt; z (2MB) overlays [512K,2.5M)
  float* ws = (float*)d_ws;
  float* hp = ws;
  float* ctx = ws;
  unsigned short* Wt = (unsigned short*)(ws + 131072);
  float* z = ws + 131072;

  const bool bigws = ws_size >= 2621440;  // 2.5 MB needed for z path

  hipMemsetAsync(alpha, 0, Bq * Tq * sizeof(float), stream);
  hipMemsetAsync(hp, 0, Bq * Hq * sizeof(float), stream);
  convW_k<<<256, 256, 0, stream>>>(W_i2h, Wt);
  hsplit_k<<<512, 256, 0, stream>>>(prev_h, W_h2h, hp);
  dim3 g4(2, 512);
  fused_score4_k<<<g4, 1024, 0, stream>>>(batch_H, Wt, hp, b_h2h, w_score, alpha);
  softmax_k<<<256, 256, 0, stream>>>(alpha);
  if (bigws) {
    hipMemsetAsync(ws, 0, 2621440, stream);
    ctxsplit_k<<<1024, 256, 0, stream>>>(alpha, batch_H, ctx);
    zsplit_k<<<256, 512, 0, stream>>>(ctx, oneh, prev_h, W_lstm, U_lstm, z);
    gatesz_k<<<256, 256, 0, stream>>>(z, b_lstm, prev_c, outh, outc);
  } else {
    hipMemsetAsync(ctx, 0, Bq * Hq * sizeof(float), stream);
    ctxsplit_k<<<1024, 256, 0, stream>>>(alpha, batch_H, ctx);
    zgates2_k<<<256, 256, 0, stream>>>(ctx, oneh, prev_h, prev_c,
                                       W_lstm, U_lstm, b_lstm, outh, outc);
  }
}

// Round 5
// 407.351 us; speedup vs baseline: 1.0683x; 1.0683x over previous
//
#include <hip/hip_runtime.h>
#include <hip/hip_bf16.h>
#include <math.h>

#define Bq 256
#define Tq 256
#define Hq 512
#define Eq 96

typedef __attribute__((ext_vector_type(8))) short short8;
typedef __attribute__((ext_vector_type(4))) float f32x4;

static __device__ __forceinline__ unsigned short f2bf(float f) {
  union { float f; unsigned u; } v; v.f = f;
  unsigned r = v.u + 0x7FFF + ((v.u >> 16) & 1);
  return (unsigned short)(r >> 16);
}

static __device__ __forceinline__ ushort4 pack4(float4 v) {
  ushort4 p;
  p.x = f2bf(v.x); p.y = f2bf(v.y); p.z = f2bf(v.z); p.w = f2bf(v.w);
  return p;
}

static __device__ __forceinline__ short8 pack8(float4 a, float4 b) {
  union { short8 s; ushort4 u[2]; } r;
  r.u[0] = pack4(a); r.u[1] = pack4(b);
  return r.s;
}

static __device__ __forceinline__ float sat_tanh(float x) {
  float ax = fminf(fabsf(x), 15.0f);
  float e = __builtin_exp2f(ax * 2.885390082f);
  float t = 1.0f - 2.0f / (e + 1.0f);
  return copysignf(t, x);
}

static __device__ __forceinline__ float sat_sig(float x) {
  float cx = fmaxf(fminf(x, 30.0f), -30.0f);
  return 1.0f / (1.0f + __builtin_exp2f(-cx * 1.442695041f));
}

// ---------------- K0: W_i2h fp32 [K][N] -> bf16 transposed [N][K] ----------
__global__ __launch_bounds__(256) void convW_k(const float* __restrict__ W,
                                               unsigned short* __restrict__ Wt) {
  __shared__ float tile[32][33];
  int bx = blockIdx.x & 15, by = blockIdx.x >> 4;
  int tx = threadIdx.x & 31, ty = threadIdx.x >> 5;
  #pragma unroll
  for (int i = 0; i < 32; i += 8)
    tile[ty + i][tx] = W[(size_t)(by * 32 + ty + i) * Hq + bx * 32 + tx];
  __syncthreads();
  #pragma unroll
  for (int i = 0; i < 32; i += 8)
    Wt[(size_t)(bx * 32 + ty + i) * Hq + by * 32 + tx] = f2bf(tile[tx][ty + i]);
}

// ---------------- K1: hp partial GEMM, K-split, atomicAdd ------------------
__global__ __launch_bounds__(256) void hsplit_k(const float* __restrict__ ph,
                                                const float* __restrict__ Whh,
                                                float* __restrict__ hp) {
  __shared__ __align__(16) float xs[8][128];
  const int ks = blockIdx.x & 3;
  const int nc = (blockIdx.x >> 2) & 3;
  const int bg = blockIdx.x >> 4;
  const int tid = threadIdx.x;
  const int row0 = bg * 8;
  const int d0 = ks * 128;
  for (int i = tid; i < 8 * 32; i += 256) {
    int r = i >> 5, dd = (i & 31) * 4;
    *(float4*)&xs[r][dd] = *(const float4*)&ph[(size_t)(row0 + r) * Hq + d0 + dd];
  }
  __syncthreads();
  const int rt = tid >> 6;
  const int ct = tid & 63;
  const int n = nc * 128 + ct * 2;
  float a00 = 0, a01 = 0, a10 = 0, a11 = 0;
  for (int dd = 0; dd < 128; dd += 4) {
    float4 x0 = *(const float4*)&xs[rt * 2][dd];
    float4 x1 = *(const float4*)&xs[rt * 2 + 1][dd];
    #pragma unroll
    for (int j = 0; j < 4; j++) {
      float2 w = *(const float2*)&Whh[(size_t)(d0 + dd + j) * Hq + n];
      float xj0 = ((const float*)&x0)[j];
      float xj1 = ((const float*)&x1)[j];
      a00 += xj0 * w.x; a01 += xj0 * w.y;
      a10 += xj1 * w.x; a11 += xj1 * w.y;
    }
  }
  int row = row0 + rt * 2;
  atomicAdd(&hp[(size_t)row * Hq + n], a00);
  atomicAdd(&hp[(size_t)row * Hq + n + 1], a01);
  atomicAdd(&hp[(size_t)(row + 1) * Hq + n], a10);
  atomicAdd(&hp[(size_t)(row + 1) * Hq + n + 1], a11);
}

// ---------------- K2 v5: 2-phase dbuf proj GEMM, BK=64 --------------------
// BM=128 x BN=128 x BK=64, 512 thr / 8 waves (2m x 4n), acc[4][2]/wave,
// 16 MFMA/wave/step, 8 steps. Per step: issue loads(k+1) -> ds_read frags(k)
// -> MFMA -> pack+ds_write(k+1) -> ONE barrier. LDK=72 pad (2-way = free).
// Grid (4 N-chunks inner, 512 M) so A re-reads hit L2. e via atomicAdd.
#define LDKA 72

__global__ __launch_bounds__(512) void fused_score5_k(
    const float* __restrict__ A,
    const unsigned short* __restrict__ Wt,
    const float* __restrict__ hp,
    const float* __restrict__ bh,
    const float* __restrict__ wsc,
    float* __restrict__ e) {
  __shared__ unsigned short As[2][128 * LDKA];  // 36864 B
  __shared__ unsigned short Bs[2][128 * LDKA];  // 36864 B
  __shared__ float red[8][64];                  // 2048 B

  const int tid = threadIdx.x;
  const int n0 = blockIdx.x * 128;   // 0..384
  const int m0 = blockIdx.y * 128;
  const int b = m0 >> 8;
  const int wave = tid >> 6;
  const int lane = tid & 63;
  const int quad = lane >> 4;
  const int l16 = lane & 15;
  const int wm = wave >> 2;          // 0..1 : 64-row half
  const int wn4 = wave & 3;          // 0..3 : 32-col chunk

  // staging coords: thread owns a 64B k-slice of one row (A fp32, B bf16)
  const int arow = tid >> 2, aq = tid & 3;
  const float* Agp = A + (size_t)(m0 + arow) * Hq + aq * 16;
  const unsigned short* Bgp = Wt + (size_t)(n0 + arow) * Hq + aq * 16;

  f32x4 acc[4][2] = {};

  // prologue: stage k=0 into buffer 0
  {
    float4 a0[4]; uint4 b0[2];
    #pragma unroll
    for (int q = 0; q < 4; q++) a0[q] = *(const float4*)(Agp + q * 4);
    b0[0] = *(const uint4*)(Bgp);
    b0[1] = *(const uint4*)(Bgp + 8);
    *(short8*)&As[0][arow * LDKA + aq * 16] = pack8(a0[0], a0[1]);
    *(short8*)&As[0][arow * LDKA + aq * 16 + 8] = pack8(a0[2], a0[3]);
    *(uint4*)&Bs[0][arow * LDKA + aq * 16] = b0[0];
    *(uint4*)&Bs[0][arow * LDKA + aq * 16 + 8] = b0[1];
  }
  __syncthreads();

  int cur = 0;
  for (int ks = 0; ks < 8; ks++) {
    // issue next-step loads FIRST (latency hidden under this step's compute)
    float4 aN[4]; uint4 bN[2];
    if (ks < 7) {
      const int k1 = (ks + 1) * 64;
      #pragma unroll
      for (int q = 0; q < 4; q++) aN[q] = *(const float4*)(Agp + k1 + q * 4);
      bN[0] = *(const uint4*)(Bgp + k1);
      bN[1] = *(const uint4*)(Bgp + k1 + 8);
    }

    short8 af[4][2], bf[2][2];
    #pragma unroll
    for (int mi = 0; mi < 4; mi++)
      #pragma unroll
      for (int k2 = 0; k2 < 2; k2++)
        af[mi][k2] = *(const short8*)&As[cur][(wm * 64 + mi * 16 + l16) * LDKA + k2 * 32 + quad * 8];
    #pragma unroll
    for (int ni = 0; ni < 2; ni++)
      #pragma unroll
      for (int k2 = 0; k2 < 2; k2++)
        bf[ni][k2] = *(const short8*)&Bs[cur][(wn4 * 32 + ni * 16 + l16) * LDKA + k2 * 32 + quad * 8];

    #pragma unroll
    for (int k2 = 0; k2 < 2; k2++)
      #pragma unroll
      for (int mi = 0; mi < 4; mi++)
        #pragma unroll
        for (int ni = 0; ni < 2; ni++)
          acc[mi][ni] = __builtin_amdgcn_mfma_f32_16x16x32_bf16(
              af[mi][k2], bf[ni][k2], acc[mi][ni], 0, 0, 0);

    if (ks < 7) {
      *(short8*)&As[cur ^ 1][arow * LDKA + aq * 16] = pack8(aN[0], aN[1]);
      *(short8*)&As[cur ^ 1][arow * LDKA + aq * 16 + 8] = pack8(aN[2], aN[3]);
      *(uint4*)&Bs[cur ^ 1][arow * LDKA + aq * 16] = bN[0];
      *(uint4*)&Bs[cur ^ 1][arow * LDKA + aq * 16 + 8] = bN[1];
    }
    __syncthreads();
    cur ^= 1;
  }

  // epilogue: tanh + w_score dot over this wave's 32 cols
  float hv[2], wv[2];
  #pragma unroll
  for (int ni = 0; ni < 2; ni++) {
    int c = n0 + wn4 * 32 + ni * 16 + l16;
    hv[ni] = hp[(size_t)b * Hq + c] + bh[c];
    wv[ni] = wsc[c];
  }
  #pragma unroll
  for (int mi = 0; mi < 4; mi++) {
    float s[4] = {0, 0, 0, 0};
    #pragma unroll
    for (int ni = 0; ni < 2; ni++)
      #pragma unroll
      for (int r = 0; r < 4; r++)
        s[r] += sat_tanh(acc[mi][ni][r] + hv[ni]) * wv[ni];
    #pragma unroll
    for (int r = 0; r < 4; r++) {
      s[r] += __shfl_xor(s[r], 8, 64);
      s[r] += __shfl_xor(s[r], 4, 64);
      s[r] += __shfl_xor(s[r], 2, 64);
      s[r] += __shfl_xor(s[r], 1, 64);
    }
    if (l16 == 0) {
      #pragma unroll
      for (int r = 0; r < 4; r++) red[wave][mi * 16 + quad * 4 + r] = s[r];
    }
  }
  __syncthreads();
  if (tid < 128) {
    const int half = tid >> 6, ri = tid & 63;
    float t = red[half * 4 + 0][ri] + red[half * 4 + 1][ri] +
              red[half * 4 + 2][ri] + red[half * 4 + 3][ri];
    atomicAdd(&e[m0 + tid], t);
  }
}

// ---------------- K3: softmax over T per batch, IN PLACE -------------------
__global__ __launch_bounds__(256) void softmax_k(float* __restrict__ ea) {
  __shared__ float red[8];
  int b = blockIdx.x, t = threadIdx.x;
  int wave = t >> 6, lane = t & 63;
  float x = ea[b * Tq + t];
  float m = x;
  #pragma unroll
  for (int off = 32; off >= 1; off >>= 1) m = fmaxf(m, __shfl_xor(m, off, 64));
  if (lane == 0) red[wave] = m;
  __syncthreads();
  m = fmaxf(fmaxf(red[0], red[1]), fmaxf(red[2], red[3]));
  float ex = __builtin_exp2f((x - m) * 1.442695041f);
  float s = ex;
  #pragma unroll
  for (int off = 32; off >= 1; off >>= 1) s += __shfl_xor(s, off, 64);
  if (lane == 0) red[4 + wave] = s;
  __syncthreads();
  s = red[4] + red[5] + red[6] + red[7];
  ea[b * Tq + t] = ex / s;
}

// ---------------- K4: context partials, T-split, atomicAdd (r0 form) -------
__global__ __launch_bounds__(256) void ctxsplit_k(const float* __restrict__ alpha,
                                                  const float* __restrict__ bH,
                                                  float* __restrict__ ctx) {
  __shared__ float al[64];
  const int b = blockIdx.x >> 2;
  const int tc = blockIdx.x & 3;
  const int tid = threadIdx.x;
  if (tid < 64) al[tid] = alpha[b * Tq + tc * 64 + tid];
  __syncthreads();
  const float2* Hp = (const float2*)(bH + (size_t)b * Tq * Hq + (size_t)tc * 64 * Hq);
  float ax = 0.f, ay = 0.f;
  #pragma unroll 8
  for (int t = 0; t < 64; t++) {
    float a = al[t];
    float2 v = Hp[t * (Hq / 2) + tid];
    ax += a * v.x;
    ay += a * v.y;
  }
  atomicAdd(&ctx[(size_t)b * Hq + 2 * tid], ax);
  atomicAdd(&ctx[(size_t)b * Hq + 2 * tid + 1], ay);
}

// ---------------- K5a v2: z partial GEMM, 32-row blocks, K-split, atomic ---
// grid 256: bg(8:32rows) x hc(8) x ks(4). 256 thr: rt owns 8 rows x 4 cols.
// Weight traffic 294 -> 74 MB vs r0; x-reads are LDS broadcasts (free).
__global__ __launch_bounds__(256) void zsplit_k(
    const float* __restrict__ ctx, const float* __restrict__ oneh,
    const float* __restrict__ ph, const float* __restrict__ Wl,
    const float* __restrict__ Ul, float* __restrict__ z) {
  __shared__ __align__(16) float xs[32 * 280];   // 35840 B
  const int ks = blockIdx.x & 3;
  const int hc = (blockIdx.x >> 2) & 7;
  const int bg = blockIdx.x >> 5;          // 0..7
  const int tid = threadIdx.x;
  const int row0 = bg * 32;
  const int dbase = ks * 280;

  for (int i = tid; i < 32 * 280; i += 256) {
    int r = i / 280, dd = i % 280;
    int g = dbase + dd;
    float v;
    if (g < 512) v = ctx[(size_t)(row0 + r) * Hq + g];
    else if (g < 608) v = oneh[(row0 + r) * Eq + (g - 512)];
    else v = ph[(size_t)(row0 + r) * Hq + (g - 608)];
    xs[r * 280 + dd] = v;
  }
  __syncthreads();

  const int rt = tid >> 6;     // 0..3 -> rows rt*8 .. rt*8+7
  const int ct = tid & 63;
  const int c0 = ct * 4;
  const int gate = c0 >> 6;
  const int ho = c0 & 63;
  const int n = gate * 512 + hc * 64 + ho;

  float acc[8][4] = {};
  for (int dd = 0; dd < 280; dd += 4) {
    float4 xr[8];
    #pragma unroll
    for (int r = 0; r < 8; r++)
      xr[r] = *(const float4*)&xs[(rt * 8 + r) * 280 + dd];
    #pragma unroll
    for (int j = 0; j < 4; j++) {
      int g = dbase + dd + j;
      const float* wp = (g < 608) ? &Wl[(size_t)g * 2048 + n]
                                  : &Ul[(size_t)(g - 608) * 2048 + n];
      float4 w = *(const float4*)wp;
      #pragma unroll
      for (int r = 0; r < 8; r++) {
        float x = ((const float*)&xr[r])[j];
        acc[r][0] += x * w.x; acc[r][1] += x * w.y;
        acc[r][2] += x * w.z; acc[r][3] += x * w.w;
      }
    }
  }
  #pragma unroll
  for (int r = 0; r < 8; r++) {
    float* zp = &z[(size_t)(row0 + rt * 8 + r) * 2048 + n];
    #pragma unroll
    for (int j = 0; j < 4; j++) atomicAdd(zp + j, acc[r][j]);
  }
}

// ---------------- K5b: gates from z ----------------------------------------
__global__ __launch_bounds__(256) void gatesz_k(const float* __restrict__ z,
                                                const float* __restrict__ bl,
                                                const float* __restrict__ pc,
                                                float* __restrict__ outh,
                                                float* __restrict__ outc) {
  int p = blockIdx.x * 256 + threadIdx.x;
  #pragma unroll
  for (int q = 0; q < 2; q++, p += 65536) {
    int r = p >> 9, h = p & 511;
    const float* zb = z + (size_t)r * 2048;
    float gi = zb[h] + bl[h];
    float gf = zb[512 + h] + bl[512 + h];
    float gg = zb[1024 + h] + bl[1024 + h];
    float go = zb[1536 + h] + bl[1536 + h];
    float cn = sat_sig(gf) * pc[p] + sat_sig(gi) * sat_tanh(gg);
    float hn = sat_sig(go) * sat_tanh(cn);
    outh[p] = hn;
    outc[p] = cn;
  }
}

// ---------------- fallback K5 (ws too small for z): fused z-GEMM+gates -----
#define KXc 1120
__global__ __launch_bounds__(256) void zgates2_k(
    const float* __restrict__ ctx, const float* __restrict__ oneh,
    const float* __restrict__ ph, const float* __restrict__ pc,
    const float* __restrict__ Wl, const float* __restrict__ Ul,
    const float* __restrict__ bl,
    float* __restrict__ outh, float* __restrict__ outc) {
  __shared__ __align__(16) float xs[8 * KXc];
  const int bg = blockIdx.x >> 3;
  const int hc = blockIdx.x & 7;
  const int tid = threadIdx.x;
  const int row0 = bg * 8;

  for (int i = tid; i < 8 * 128; i += 256) {
    int r = i >> 7, dd = (i & 127) * 4;
    *(float4*)&xs[r * KXc + dd] = *(const float4*)&ctx[(size_t)(row0 + r) * Hq + dd];
  }
  for (int i = tid; i < 8 * 128; i += 256) {
    int r = i >> 7, dd = (i & 127) * 4;
    *(float4*)&xs[r * KXc + 608 + dd] = *(const float4*)&ph[(size_t)(row0 + r) * Hq + dd];
  }
  if (tid < 8 * 24) {
    int r = tid / 24, dd = (tid % 24) * 4;
    *(float4*)&xs[r * KXc + 512 + dd] = *(const float4*)&oneh[(row0 + r) * Eq + dd];
  }
  __syncthreads();

  const int rt = tid >> 6;
  const int ct = tid & 63;
  const int c0 = ct * 4;
  const int gate = c0 >> 6;
  const int ho = c0 & 63;
  const int n = gate * 512 + hc * 64 + ho;

  float acc0[4] = {0, 0, 0, 0};
  float acc1[4] = {0, 0, 0, 0};
  const float* xr0 = &xs[(rt * 2) * KXc];
  const float* xr1 = &xs[(rt * 2 + 1) * KXc];

  for (int d = 0; d < 608; d += 4) {
    float4 x0 = *(const float4*)&xr0[d];
    float4 x1 = *(const float4*)&xr1[d];
    #pragma unroll
    for (int j = 0; j < 4; j++) {
      float4 w = *(const float4*)&Wl[(size_t)(d + j) * 2048 + n];
      float a = ((const float*)&x0)[j], b = ((const float*)&x1)[j];
      acc0[0] += a * w.x; acc0[1] += a * w.y; acc0[2] += a * w.z; acc0[3] += a * w.w;
      acc1[0] += b * w.x; acc1[1] += b * w.y; acc1[2] += b * w.z; acc1[3] += b * w.w;
    }
  }
  for (int d = 0; d < 512; d += 4) {
    float4 x0 = *(const float4*)&xr0[608 + d];
    float4 x1 = *(const float4*)&xr1[608 + d];
    #pragma unroll
    for (int j = 0; j < 4; j++) {
      float4 w = *(const float4*)&Ul[(size_t)(d + j) * 2048 + n];
      float a = ((const float*)&x0)[j], b = ((const float*)&x1)[j];
      acc0[0] += a * w.x; acc0[1] += a * w.y; acc0[2] += a * w.z; acc0[3] += a * w.w;
      acc1[0] += b * w.x; acc1[1] += b * w.y; acc1[2] += b * w.z; acc1[3] += b * w.w;
    }
  }

  __syncthreads();
  float* zs = xs;
  #pragma unroll
  for (int j = 0; j < 4; j++) {
    zs[(rt * 2) * 256 + c0 + j] = acc0[j];
    zs[(rt * 2 + 1) * 256 + c0 + j] = acc1[j];
  }
  __syncthreads();

  #pragma unroll
  for (int p = tid; p < 512; p += 256) {
    int r = p >> 6, o = p & 63;
    int h = hc * 64 + o;
    int grow = row0 + r;
    float gi = zs[r * 256 + o]       + bl[h];
    float gf = zs[r * 256 + 64 + o]  + bl[512 + h];
    float gg = zs[r * 256 + 128 + o] + bl[1024 + h];
    float go = zs[r * 256 + 192 + o] + bl[1536 + h];
    float cn = sat_sig(gf) * pc[(size_t)grow * Hq + h] + sat_sig(gi) * sat_tanh(gg);
    float hn = sat_sig(go) * sat_tanh(cn);
    outh[(size_t)grow * Hq + h] = hn;
    outc[(size_t)grow * Hq + h] = cn;
  }
}

extern "C" void kernel_launch(void* const* d_in, const int* in_sizes, int n_in,
                              void* d_out, int out_size, void* d_ws, size_t ws_size,
                              hipStream_t stream) {
  const float* prev_h = (const float*)d_in[0];
  const float* prev_c = (const float*)d_in[1];
  const float* batch_H = (const float*)d_in[2];
  const float* oneh = (const float*)d_in[3];
  const float* W_i2h = (const float*)d_in[4];
  const float* W_h2h = (const float*)d_in[5];
  const float* b_h2h = (const float*)d_in[6];
  const float* w_score = (const float*)d_in[7];
  const float* W_lstm = (const float*)d_in[8];
  const float* U_lstm = (const float*)d_in[9];
  const float* b_lstm = (const float*)d_in[10];

  float* out = (float*)d_out;
  float* outh = out;
  float* outc = out + Bq * Hq;
  float* alpha = out + 2 * Bq * Hq;

  // ws layout: [0,512K) hp -> ctx; [512K,1M) Wt; z (2MB) overlays [512K,2.5M)
  float* ws = (float*)d_ws;
  float* hp = ws;
  float* ctx = ws;
  unsigned short* Wt = (unsigned short*)(ws + 131072);
  float* z = ws + 131072;

  const bool bigws = ws_size >= 2621440;  // 2.5 MB needed for z path

  hipMemsetAsync(alpha, 0, Bq * Tq * sizeof(float), stream);
  hipMemsetAsync(hp, 0, Bq * Hq * sizeof(float), stream);
  convW_k<<<256, 256, 0, stream>>>(W_i2h, Wt);
  hsplit_k<<<512, 256, 0, stream>>>(prev_h, W_h2h, hp);
  dim3 g5(4, 512);
  fused_score5_k<<<g5, 512, 0, stream>>>(batch_H, Wt, hp, b_h2h, w_score, alpha);
  softmax_k<<<256, 256, 0, stream>>>(alpha);
  if (bigws) {
    hipMemsetAsync(ws, 0, 2621440, stream);
    ctxsplit_k<<<1024, 256, 0, stream>>>(alpha, batch_H, ctx);
    zsplit_k<<<256, 256, 0, stream>>>(ctx, oneh, prev_h, W_lstm, U_lstm, z);
    gatesz_k<<<256, 256, 0, stream>>>(z, b_lstm, prev_c, outh, outc);
  } else {
    hipMemsetAsync(ctx, 0, Bq * Hq * sizeof(float), stream);
    ctxsplit_k<<<1024, 256, 0, stream>>>(alpha, batch_H, ctx);
    zgates2_k<<<256, 256, 0, stream>>>(ctx, oneh, prev_h, prev_c,
                                       W_lstm, U_lstm, b_lstm, outh, outc);
  }
}